// Round 3
// baseline (296.488 us; speedup 1.0000x reference)
//
#include <hip/hip_runtime.h>
#include <hip/hip_fp16.h>

#define NQ 20

__device__ __forceinline__ float bcast_first(float x) {
    return __int_as_float(__builtin_amdgcn_readfirstlane(__float_as_int(x)));
}

// RX butterfly, symmetric form: new = C*mine + SV*(partner.im, -partner.re)
__device__ __forceinline__ void bfly(float C, float SV, float2& a, float2& b) {
    float2 na = make_float2(C * a.x + SV * b.y, C * a.y - SV * b.x);
    float2 nb = make_float2(C * b.x + SV * a.y, C * b.y - SV * a.x);
    a = na; b = nb;
}

// vectorized over two complex packed in float4 (same butterfly both halves)
__device__ __forceinline__ void bfly4(float C, float SV, float4& a, float4& b) {
    float4 na = make_float4(C*a.x + SV*b.y, C*a.y - SV*b.x, C*a.z + SV*b.w, C*a.w - SV*b.z);
    float4 nb = make_float4(C*b.x + SV*a.y, C*b.y - SV*a.x, C*b.z + SV*a.w, C*b.w - SV*a.z);
    a = na; b = nb;
}

__device__ __forceinline__ unsigned int pack_h2(float re, float im) {
    __half2 h = __floats2half2_rn(re, im);
    return *(unsigned int*)&h;
}
__device__ __forceinline__ float2 unpack_h2(unsigned int u) {
    return __half22float2(*(__half2*)&u);
}

// --- non-temporal access helpers (read-once / write-once buffers) ----------
typedef float f32x4 __attribute__((ext_vector_type(4)));
typedef float f32x2 __attribute__((ext_vector_type(2)));

__device__ __forceinline__ float4 nt_load_f4(const float* p) {
    f32x4 t = __builtin_nontemporal_load((const f32x4*)p);
    return make_float4(t[0], t[1], t[2], t[3]);
}
__device__ __forceinline__ void nt_store_f2(float2* p, float2 v) {
    f32x2 t; t[0] = v.x; t[1] = v.y;
    __builtin_nontemporal_store(t, (f32x2*)p);
}
__device__ __forceinline__ void nt_store_f4(float* p, float4 v) {
    f32x4 t; t[0] = v.x; t[1] = v.y; t[2] = v.z; t[3] = v.w;
    __builtin_nontemporal_store(t, (f32x4*)p);
}

// swizzled LDS index for pass1: XOR bits 2..4 by bits 7..9 of the local index
__device__ __forceinline__ int swz1(int l) { return l ^ (((l >> 7) & 7) << 2); }

// ---------------------------------------------------------------------------
// Pass 1 (fp16 intermediate): state bits 0..10 (qubits 19..9). One wave owns
// 2048 contiguous complex. phi is read-once -> non-temporal loads (keep L3
// for the ws intermediate). ws stores stay cached: pass2 re-reads them.
// ---------------------------------------------------------------------------
__global__ __launch_bounds__(64) void rx_pass1_h(
        const float* __restrict__ phi, const float* __restrict__ thetas,
        unsigned int* __restrict__ ws) {
    __shared__ float2 lds[2048];                    // 16 KiB
    const int lane = threadIdx.x;
    const int W = blockIdx.x;                       // [0, 8192)
    const int b = W >> 9;
    const int base = (W & 511) << 11;
    const float* ph = phi + ((size_t)b << NQ) + base;
    unsigned int* wp = ws + ((size_t)b << NQ) + base;

    float c[11], sv[11];
#pragma unroll
    for (int beta = 0; beta < 11; ++beta) {
        float th = 0.5f * thetas[b * NQ + (NQ - 1 - beta)];
        c[beta]  = bcast_first(cosf(th));
        sv[beta] = bcast_first(sinf(th));
    }

    float2 v[32];
#pragma unroll
    for (int k4 = 0; k4 < 8; ++k4) {
        float4 t = nt_load_f4(ph + (k4 << 8) + (lane << 2));
        v[k4 * 4 + 0] = make_float2(t.x, 0.f);
        v[k4 * 4 + 1] = make_float2(t.y, 0.f);
        v[k4 * 4 + 2] = make_float2(t.z, 0.f);
        v[k4 * 4 + 3] = make_float2(t.w, 0.f);
    }

    const int regbit1[5]  = {0, 1, 8, 9, 10};
    const int regmask1[5] = {1, 2, 4, 8, 16};
#pragma unroll
    for (int t = 0; t < 5; ++t) {
        const float C = c[regbit1[t]], SV = sv[regbit1[t]];
        const int m = regmask1[t];
#pragma unroll
        for (int r = 0; r < 32; ++r)
            if (!(r & m)) bfly(C, SV, v[r], v[r | m]);
    }

#pragma unroll
    for (int k4 = 0; k4 < 8; ++k4) {
        int low0 = (k4 << 8) + (lane << 2);
        int s0 = swz1(low0);
        *(float4*)&lds[s0]     = make_float4(v[k4*4+0].x, v[k4*4+0].y, v[k4*4+1].x, v[k4*4+1].y);
        *(float4*)&lds[s0 + 2] = make_float4(v[k4*4+2].x, v[k4*4+2].y, v[k4*4+3].x, v[k4*4+3].y);
    }
    __syncthreads();

    {
        const int g = lane >> 2, lam = lane & 3;
        float2 w2[32];
#pragma unroll
        for (int r = 0; r < 32; ++r) {
            int l = (g << 7) | (r << 2) | lam;
            w2[r] = lds[swz1(l)];
        }
#pragma unroll
        for (int t = 0; t < 5; ++t) {
            const float C = c[2 + t], SV = sv[2 + t];
            const int m = 1 << t;
#pragma unroll
            for (int r = 0; r < 32; ++r)
                if (!(r & m)) bfly(C, SV, w2[r], w2[r | m]);
        }
#pragma unroll
        for (int r = 0; r < 32; ++r) {
            int l = (g << 7) | (r << 2) | lam;
            lds[swz1(l)] = w2[r];
        }
    }
    __syncthreads();

    // Stage 3: read mapping gathers bit0 (float4 pair) + bit1 (m&1) so each
    // lane ends with 4-consecutive-complex groups -> uint4 stores.
    // l0 bits: 0=pair, 1=m0, 2..6=lane0..4, 7=m1, 8=lane5, 9..10=m2..3.
    float4 u[16];
#pragma unroll
    for (int m = 0; m < 16; ++m) {
        int l0 = ((m & 1) << 1) | ((lane & 31) << 2) | (((m >> 1) & 1) << 7)
               | (((lane >> 5) & 1) << 8) | (((m >> 2) & 3) << 9);
        u[m] = *(float4*)&lds[swz1(l0)];
    }
    {
        const float C = c[7], SV = sv[7];   // bit 7 pairs: (m, m|2)
#pragma unroll
        for (int m = 0; m < 16; ++m)
            if (!(m & 2)) bfly4(C, SV, u[m], u[m | 2]);
    }
#pragma unroll
    for (int k = 0; k < 8; ++k) {
        int X = ((lane & 31) << 2) | ((k & 1) << 7)
              | (((lane >> 5) & 1) << 8) | ((k >> 1) << 9);
        uint4 pk;
        pk.x = pack_h2(u[2*k].x,     u[2*k].y);
        pk.y = pack_h2(u[2*k].z,     u[2*k].w);
        pk.z = pack_h2(u[2*k + 1].x, u[2*k + 1].y);
        pk.w = pack_h2(u[2*k + 1].z, u[2*k + 1].w);
        *(uint4*)(wp + X) = pk;                 // cached store: pass2 re-reads
    }
}

// ---------------------------------------------------------------------------
// Pass 2 (fp16 in LDS + global-in): bits 11..19 (qubits 8..0).
// Tile = 512 h x 32 low = 16384 complex half2 = 64 KiB LDS, 512 threads.
// ws reads cached (should be L3 hits); out stores NON-TEMPORAL (write-once,
// never re-read -> don't evict ws from L3).
// Granule swizzle g' = g ^ (h&7) (4-uint granules, preserves uint4).
// ---------------------------------------------------------------------------
__device__ __forceinline__ int p2idx(int h, int g) {   // g = low>>2 granule [0,8)
    return (h << 5) + (((g ^ (h & 7)) & 7) << 2);
}

__global__ __launch_bounds__(512, 4) void rx_pass2_h(
        const float* __restrict__ thetas, const unsigned int* __restrict__ ws,
        float2* __restrict__ out) {
    __shared__ unsigned int buf[16384];             // 64 KiB
    const int tid = threadIdx.x;
    const int b = blockIdx.x >> 6;
    const int lb = blockIdx.x & 63;                 // 64 chunks of 32 low offsets
    const unsigned int* pin = ws + ((size_t)b << NQ) + (lb << 5);
    float2* pout = out + ((size_t)b << NQ) + (lb << 5);

    // h-bit i <-> qubit 8-i
    float c[9], sv[9];
#pragma unroll
    for (int i = 0; i < 9; ++i) {
        float th = 0.5f * thetas[b * NQ + (8 - i)];
        c[i]  = bcast_first(cosf(th));
        sv[i] = bcast_first(sinf(th));
    }

    // Stage A: global (half2) -> LDS, one uint4 (4 cpx, 16 B) per thread per iter
#pragma unroll
    for (int i = 0; i < 8; ++i) {
        int f = (i << 9) | tid;                     // [0, 4096)
        int h = f >> 3, q = f & 7;                  // row, quad-of-4-complex
        uint4 t = *(const uint4*)(pin + h * 2048 + (q << 2));
        *(uint4*)&buf[p2idx(h, q)] = t;
    }
    __syncthreads();

    // Stage B2: h bits 5..8 (qubits 3..0), regs m in [0,16), per-thread low-pair
    {
        const int hl = tid & 31;                    // h bits 0..4
        const int j  = tid >> 5;                    // low pair [0,16)
        const int g = j >> 1, off = (j & 1) << 1;
        float4 w[16];
#pragma unroll
        for (int m = 0; m < 16; ++m) {
            int h = (m << 5) | hl;
            uint2 t = *(const uint2*)&buf[p2idx(h, g) + off];
            float2 a = unpack_h2(t.x), bb = unpack_h2(t.y);
            w[m] = make_float4(a.x, a.y, bb.x, bb.y);
        }
#pragma unroll
        for (int t = 0; t < 4; ++t) {
            const float C = c[5 + t], SV = sv[5 + t];
            const int msk = 1 << t;
#pragma unroll
            for (int m = 0; m < 16; ++m)
                if (!(m & msk)) bfly4(C, SV, w[m], w[m | msk]);
        }
#pragma unroll
        for (int m = 0; m < 16; ++m) {
            int h = (m << 5) | hl;
            uint2 t;
            t.x = pack_h2(w[m].x, w[m].y);
            t.y = pack_h2(w[m].z, w[m].w);
            *(uint2*)&buf[p2idx(h, g) + off] = t;
        }
    }
    __syncthreads();

    // Stage B1: h bits 0..4 (qubits 8..4), regs r in [0,32), nt fp32 store
    {
        const int hh = tid >> 5;                    // h bits 5..8
        const int ll = tid & 31;                    // low offset [0,32)
        const int g = ll >> 2, off = ll & 3;
        float2 v[32];
#pragma unroll
        for (int r = 0; r < 32; ++r) {
            int h = (hh << 5) | r;
            v[r] = unpack_h2(buf[p2idx(h, g) + off]);
        }
#pragma unroll
        for (int t = 0; t < 5; ++t) {
            const float C = c[t], SV = sv[t];
            const int msk = 1 << t;
#pragma unroll
            for (int r = 0; r < 32; ++r)
                if (!(r & msk)) bfly(C, SV, v[r], v[r | msk]);
        }
#pragma unroll
        for (int r = 0; r < 32; ++r) {
            int h = (hh << 5) | r;
            nt_store_f2(pout + h * 2048 + ll, v[r]);    // 256 B contiguous / 32 lanes
        }
    }
}

// ---------------------------------------------------------------------------
// Fallback fp32 path (proven kernels) in case ws is too small.
// ---------------------------------------------------------------------------
__global__ __launch_bounds__(64) void rx_pass1(
        const float* __restrict__ phi, const float* __restrict__ thetas,
        float2* __restrict__ out) {
    __shared__ float2 lds[2048];
    const int lane = threadIdx.x;
    const int W = blockIdx.x;
    const int b = W >> 9;
    const int base = (W & 511) << 11;
    const float* ph = phi + ((size_t)b << NQ) + base;
    float2* op = out + ((size_t)b << NQ) + base;

    float c[11], sv[11];
#pragma unroll
    for (int beta = 0; beta < 11; ++beta) {
        float th = 0.5f * thetas[b * NQ + (NQ - 1 - beta)];
        c[beta]  = bcast_first(cosf(th));
        sv[beta] = bcast_first(sinf(th));
    }

    float2 v[32];
#pragma unroll
    for (int k4 = 0; k4 < 8; ++k4) {
        float4 t = nt_load_f4(ph + (k4 << 8) + (lane << 2));
        v[k4 * 4 + 0] = make_float2(t.x, 0.f);
        v[k4 * 4 + 1] = make_float2(t.y, 0.f);
        v[k4 * 4 + 2] = make_float2(t.z, 0.f);
        v[k4 * 4 + 3] = make_float2(t.w, 0.f);
    }

    const int regbit1[5]  = {0, 1, 8, 9, 10};
    const int regmask1[5] = {1, 2, 4, 8, 16};
#pragma unroll
    for (int t = 0; t < 5; ++t) {
        const float C = c[regbit1[t]], SV = sv[regbit1[t]];
        const int m = regmask1[t];
#pragma unroll
        for (int r = 0; r < 32; ++r)
            if (!(r & m)) bfly(C, SV, v[r], v[r | m]);
    }

#pragma unroll
    for (int k4 = 0; k4 < 8; ++k4) {
        int low0 = (k4 << 8) + (lane << 2);
        int s0 = swz1(low0);
        *(float4*)&lds[s0]     = make_float4(v[k4*4+0].x, v[k4*4+0].y, v[k4*4+1].x, v[k4*4+1].y);
        *(float4*)&lds[s0 + 2] = make_float4(v[k4*4+2].x, v[k4*4+2].y, v[k4*4+3].x, v[k4*4+3].y);
    }
    __syncthreads();

    {
        const int g = lane >> 2, lam = lane & 3;
        float2 w2[32];
#pragma unroll
        for (int r = 0; r < 32; ++r) {
            int l = (g << 7) | (r << 2) | lam;
            w2[r] = lds[swz1(l)];
        }
#pragma unroll
        for (int t = 0; t < 5; ++t) {
            const float C = c[2 + t], SV = sv[2 + t];
            const int m = 1 << t;
#pragma unroll
            for (int r = 0; r < 32; ++r)
                if (!(r & m)) bfly(C, SV, w2[r], w2[r | m]);
        }
#pragma unroll
        for (int r = 0; r < 32; ++r) {
            int l = (g << 7) | (r << 2) | lam;
            lds[swz1(l)] = w2[r];
        }
    }
    __syncthreads();

    float4 u[16];
#pragma unroll
    for (int m = 0; m < 16; ++m) {
        int l0 = (lane << 1) | ((m & 1) << 7) | (((m >> 1) & 1) << 8)
               | (((m >> 2) & 1) << 9) | (((m >> 3) & 1) << 10);
        u[m] = *(float4*)&lds[swz1(l0)];
    }
    {
        const float C = c[7], SV = sv[7];
#pragma unroll
        for (int m = 0; m < 16; m += 2) {
            float4 A = u[m], B = u[m + 1];
            u[m]     = make_float4(C*A.x + SV*B.y, C*A.y - SV*B.x, C*A.z + SV*B.w, C*A.w - SV*B.z);
            u[m + 1] = make_float4(C*B.x + SV*A.y, C*B.y - SV*A.x, C*B.z + SV*A.w, C*B.w - SV*A.z);
        }
    }
#pragma unroll
    for (int m = 0; m < 16; ++m) {
        int l0 = (lane << 1) | ((m & 1) << 7) | (((m >> 1) & 1) << 8)
               | (((m >> 2) & 1) << 9) | (((m >> 3) & 1) << 10);
        *(float4*)(op + l0) = u[m];
    }
}

__device__ __forceinline__ int ppos(int h, int q) {
    return (h << 4) + (((q ^ (h & 7) ^ ((h >> 5) & 7)) & 7) << 1);
}

__global__ __launch_bounds__(256) void rx_pass2(
        const float* __restrict__ thetas, float2* __restrict__ out) {
    __shared__ float2 buf[8192];
    const int tid = threadIdx.x;
    const int b = blockIdx.x >> 7;
    const int lb = blockIdx.x & 127;
    float2* p = out + ((size_t)b << NQ) + (lb << 4);

    float c[9], sv[9];
#pragma unroll
    for (int i = 0; i < 9; ++i) {
        float th = 0.5f * thetas[b * NQ + (8 - i)];
        c[i]  = bcast_first(cosf(th));
        sv[i] = bcast_first(sinf(th));
    }

#pragma unroll
    for (int i = 0; i < 16; ++i) {
        int f = (i << 8) | tid;
        int h = f >> 3, j = f & 7;
        float4 t = *(const float4*)(p + h * 2048 + (j << 1));
        *(float4*)&buf[ppos(h, j)] = t;
    }
    __syncthreads();

    {
        const int hl = tid & 31;
        const int j  = tid >> 5;
        float4 w[16];
#pragma unroll
        for (int m = 0; m < 16; ++m)
            w[m] = *(float4*)&buf[ppos((m << 5) | hl, j)];
#pragma unroll
        for (int t = 0; t < 4; ++t) {
            const float C = c[5 + t], SV = sv[5 + t];
            const int msk = 1 << t;
#pragma unroll
            for (int m = 0; m < 16; ++m)
                if (!(m & msk)) bfly4(C, SV, w[m], w[m | msk]);
        }
#pragma unroll
        for (int m = 0; m < 16; ++m)
            *(float4*)&buf[ppos((m << 5) | hl, j)] = w[m];
    }
    __syncthreads();

    {
        const int hh = tid >> 4;
        const int ll = tid & 15;
        float2 v[32];
#pragma unroll
        for (int r = 0; r < 32; ++r) {
            int h = (hh << 5) | r;
            v[r] = buf[ppos(h, ll >> 1) + (ll & 1)];
        }
#pragma unroll
        for (int t = 0; t < 5; ++t) {
            const float C = c[t], SV = sv[t];
            const int msk = 1 << t;
#pragma unroll
            for (int r = 0; r < 32; ++r)
                if (!(r & msk)) bfly(C, SV, v[r], v[r | msk]);
        }
#pragma unroll
        for (int r = 0; r < 32; ++r) {
            int h = (hh << 5) | r;
            p[h * 2048 + ll] = v[r];
        }
    }
}

extern "C" void kernel_launch(void* const* d_in, const int* in_sizes, int n_in,
                              void* d_out, int out_size, void* d_ws, size_t ws_size,
                              hipStream_t stream) {
    const float* phi    = (const float*)d_in[0];
    const float* thetas = (const float*)d_in[1];
    float2* out = (float2*)d_out;
    const size_t inter_bytes = ((size_t)16 << NQ) * 4;   // 64 MiB half2 intermediate
    if (d_ws != nullptr && ws_size >= inter_bytes) {
        unsigned int* ws = (unsigned int*)d_ws;
        rx_pass1_h<<<8192, 64, 0, stream>>>(phi, thetas, ws);
        rx_pass2_h<<<1024, 512, 0, stream>>>(thetas, ws, out);
    } else {
        rx_pass1<<<8192, 64, 0, stream>>>(phi, thetas, out);
        rx_pass2<<<2048, 256, 0, stream>>>(thetas, out);
    }
}

// Round 4
// 266.234 us; speedup vs baseline: 1.1136x; 1.1136x over previous
//
#include <hip/hip_runtime.h>
#include <hip/hip_fp16.h>

#define NQ 20

__device__ __forceinline__ float bcast_first(float x) {
    return __int_as_float(__builtin_amdgcn_readfirstlane(__float_as_int(x)));
}

// RX butterfly, symmetric form: new = C*mine + SV*(partner.im, -partner.re)
__device__ __forceinline__ void bfly(float C, float SV, float2& a, float2& b) {
    float2 na = make_float2(C * a.x + SV * b.y, C * a.y - SV * b.x);
    float2 nb = make_float2(C * b.x + SV * a.y, C * b.y - SV * a.x);
    a = na; b = nb;
}

// vectorized over two complex packed in float4 (same butterfly both halves)
__device__ __forceinline__ void bfly4(float C, float SV, float4& a, float4& b) {
    float4 na = make_float4(C*a.x + SV*b.y, C*a.y - SV*b.x, C*a.z + SV*b.w, C*a.w - SV*b.z);
    float4 nb = make_float4(C*b.x + SV*a.y, C*b.y - SV*a.x, C*b.z + SV*a.w, C*b.w - SV*a.z);
    a = na; b = nb;
}

__device__ __forceinline__ unsigned int pack_h2(float re, float im) {
    __half2 h = __floats2half2_rn(re, im);
    return *(unsigned int*)&h;
}
__device__ __forceinline__ float2 unpack_h2(unsigned int u) {
    return __half22float2(*(__half2*)&u);
}

// swizzled LDS index for pass1: XOR bits 2..4 by bits 7..9 of the local index
__device__ __forceinline__ int swz1(int l) { return l ^ (((l >> 7) & 7) << 2); }

// ---------------------------------------------------------------------------
// Trig table: cos/sin of thetas/2 for all B*NQ angles, computed once.
// Saves 22 libm sincos per thread across 9216 blocks in the main kernels.
// ---------------------------------------------------------------------------
__global__ void rx_trig(const float* __restrict__ thetas, float2* __restrict__ tab) {
    int i = threadIdx.x;
    if (i < 16 * NQ) {
        float th = 0.5f * thetas[i];
        tab[i] = make_float2(cosf(th), sinf(th));
    }
}

// ---------------------------------------------------------------------------
// Pass 1 (fp16 intermediate): state bits 0..10 (qubits 19..9). One wave owns
// 2048 contiguous complex. LDS is now half2 (8 KiB/block -> 20 blocks/CU,
// double the occupancy of the 16 KiB fp32 version). Registers stay fp32.
// ---------------------------------------------------------------------------
__global__ __launch_bounds__(64) void rx_pass1_h(
        const float* __restrict__ phi, const float2* __restrict__ tab,
        unsigned int* __restrict__ ws) {
    __shared__ unsigned int lds[2048];              // 8 KiB (half2 per complex)
    const int lane = threadIdx.x;
    const int W = blockIdx.x;                       // [0, 8192)
    const int b = W >> 9;
    const int base = (W & 511) << 11;
    const float* ph = phi + ((size_t)b << NQ) + base;
    unsigned int* wp = ws + ((size_t)b << NQ) + base;

    float c[11], sv[11];
#pragma unroll
    for (int beta = 0; beta < 11; ++beta) {
        float2 t = tab[b * NQ + (NQ - 1 - beta)];
        c[beta]  = bcast_first(t.x);
        sv[beta] = bcast_first(t.y);
    }

    float2 v[32];
#pragma unroll
    for (int k4 = 0; k4 < 8; ++k4) {
        float4 t = *(const float4*)(ph + (k4 << 8) + (lane << 2));
        v[k4 * 4 + 0] = make_float2(t.x, 0.f);
        v[k4 * 4 + 1] = make_float2(t.y, 0.f);
        v[k4 * 4 + 2] = make_float2(t.z, 0.f);
        v[k4 * 4 + 3] = make_float2(t.w, 0.f);
    }

    const int regbit1[5]  = {0, 1, 8, 9, 10};
    const int regmask1[5] = {1, 2, 4, 8, 16};
#pragma unroll
    for (int t = 0; t < 5; ++t) {
        const float C = c[regbit1[t]], SV = sv[regbit1[t]];
        const int m = regmask1[t];
#pragma unroll
        for (int r = 0; r < 32; ++r)
            if (!(r & m)) bfly(C, SV, v[r], v[r | m]);
    }

    // stage-1 exchange write: 4 cpx packed to one uint4 (16B) per k4
#pragma unroll
    for (int k4 = 0; k4 < 8; ++k4) {
        int low0 = (k4 << 8) + (lane << 2);
        int s0 = swz1(low0);
        uint4 pk;
        pk.x = pack_h2(v[k4*4+0].x, v[k4*4+0].y);
        pk.y = pack_h2(v[k4*4+1].x, v[k4*4+1].y);
        pk.z = pack_h2(v[k4*4+2].x, v[k4*4+2].y);
        pk.w = pack_h2(v[k4*4+3].x, v[k4*4+3].y);
        *(uint4*)&lds[s0] = pk;
    }
    __syncthreads();

    {
        const int g = lane >> 2, lam = lane & 3;
        float2 w2[32];
#pragma unroll
        for (int r = 0; r < 32; ++r) {
            int l = (g << 7) | (r << 2) | lam;
            w2[r] = unpack_h2(lds[swz1(l)]);
        }
#pragma unroll
        for (int t = 0; t < 5; ++t) {
            const float C = c[2 + t], SV = sv[2 + t];
            const int m = 1 << t;
#pragma unroll
            for (int r = 0; r < 32; ++r)
                if (!(r & m)) bfly(C, SV, w2[r], w2[r | m]);
        }
#pragma unroll
        for (int r = 0; r < 32; ++r) {
            int l = (g << 7) | (r << 2) | lam;
            lds[swz1(l)] = pack_h2(w2[r].x, w2[r].y);
        }
    }
    __syncthreads();

    // Stage 3: read mapping gathers bit0 (cpx pair) + bit1 (m&1) so each
    // lane ends with 4-consecutive-complex groups -> uint4 stores.
    // l0 bits: 0=pair, 1=m0, 2..6=lane0..4, 7=m1, 8=lane5, 9..10=m2..3.
    float2 u2[32];
#pragma unroll
    for (int m = 0; m < 16; ++m) {
        int l0 = ((m & 1) << 1) | ((lane & 31) << 2) | (((m >> 1) & 1) << 7)
               | (((lane >> 5) & 1) << 8) | (((m >> 2) & 3) << 9);
        uint2 t = *(uint2*)&lds[swz1(l0)];
        u2[2*m]     = unpack_h2(t.x);
        u2[2*m + 1] = unpack_h2(t.y);
    }
    {
        const float C = c[7], SV = sv[7];   // bit 7 pairs: (m, m|2)
#pragma unroll
        for (int m = 0; m < 16; ++m)
            if (!(m & 2)) {
                bfly(C, SV, u2[2*m],     u2[2*(m|2)]);
                bfly(C, SV, u2[2*m + 1], u2[2*(m|2) + 1]);
            }
    }
#pragma unroll
    for (int k = 0; k < 8; ++k) {
        int X = ((lane & 31) << 2) | ((k & 1) << 7)
              | (((lane >> 5) & 1) << 8) | ((k >> 1) << 9);
        uint4 pk;
        pk.x = pack_h2(u2[4*k + 0].x, u2[4*k + 0].y);
        pk.y = pack_h2(u2[4*k + 1].x, u2[4*k + 1].y);
        pk.z = pack_h2(u2[4*k + 2].x, u2[4*k + 2].y);
        pk.w = pack_h2(u2[4*k + 3].x, u2[4*k + 3].y);
        *(uint4*)(wp + X) = pk;                 // 16 B/lane, 512 B contiguous
    }
}

// ---------------------------------------------------------------------------
// Pass 2 (fp16 in LDS + global-in): bits 11..19 (qubits 8..0).
// Tile = 512 h x 32 low = 16384 complex half2 = 64 KiB LDS, 512 threads.
// Plain cached loads/stores (nt falsified in R3: caused HBM RMW).
// Granule swizzle g' = g ^ (h&7) (4-uint granules, preserves uint4).
// ---------------------------------------------------------------------------
__device__ __forceinline__ int p2idx(int h, int g) {   // g = low>>2 granule [0,8)
    return (h << 5) + (((g ^ (h & 7)) & 7) << 2);
}

__global__ __launch_bounds__(512, 4) void rx_pass2_h(
        const float2* __restrict__ tab, const unsigned int* __restrict__ ws,
        float2* __restrict__ out) {
    __shared__ unsigned int buf[16384];             // 64 KiB
    const int tid = threadIdx.x;
    const int b = blockIdx.x >> 6;
    const int lb = blockIdx.x & 63;                 // 64 chunks of 32 low offsets
    const unsigned int* pin = ws + ((size_t)b << NQ) + (lb << 5);
    float2* pout = out + ((size_t)b << NQ) + (lb << 5);

    // h-bit i <-> qubit 8-i
    float c[9], sv[9];
#pragma unroll
    for (int i = 0; i < 9; ++i) {
        float2 t = tab[b * NQ + (8 - i)];
        c[i]  = bcast_first(t.x);
        sv[i] = bcast_first(t.y);
    }

    // Stage A: global (half2) -> LDS, one uint4 (4 cpx, 16 B) per thread per iter
#pragma unroll
    for (int i = 0; i < 8; ++i) {
        int f = (i << 9) | tid;                     // [0, 4096)
        int h = f >> 3, q = f & 7;                  // row, quad-of-4-complex
        uint4 t = *(const uint4*)(pin + h * 2048 + (q << 2));
        *(uint4*)&buf[p2idx(h, q)] = t;
    }
    __syncthreads();

    // Stage B2: h bits 5..8 (qubits 3..0), regs m in [0,16), per-thread low-pair
    {
        const int hl = tid & 31;                    // h bits 0..4
        const int j  = tid >> 5;                    // low pair [0,16)
        const int g = j >> 1, off = (j & 1) << 1;
        float4 w[16];
#pragma unroll
        for (int m = 0; m < 16; ++m) {
            int h = (m << 5) | hl;
            uint2 t = *(const uint2*)&buf[p2idx(h, g) + off];
            float2 a = unpack_h2(t.x), bb = unpack_h2(t.y);
            w[m] = make_float4(a.x, a.y, bb.x, bb.y);
        }
#pragma unroll
        for (int t = 0; t < 4; ++t) {
            const float C = c[5 + t], SV = sv[5 + t];
            const int msk = 1 << t;
#pragma unroll
            for (int m = 0; m < 16; ++m)
                if (!(m & msk)) bfly4(C, SV, w[m], w[m | msk]);
        }
#pragma unroll
        for (int m = 0; m < 16; ++m) {
            int h = (m << 5) | hl;
            uint2 t;
            t.x = pack_h2(w[m].x, w[m].y);
            t.y = pack_h2(w[m].z, w[m].w);
            *(uint2*)&buf[p2idx(h, g) + off] = t;
        }
    }
    __syncthreads();

    // Stage B1: h bits 0..4 (qubits 8..4), regs r in [0,32), direct fp32 store
    {
        const int hh = tid >> 5;                    // h bits 5..8
        const int ll = tid & 31;                    // low offset [0,32)
        const int g = ll >> 2, off = ll & 3;
        float2 v[32];
#pragma unroll
        for (int r = 0; r < 32; ++r) {
            int h = (hh << 5) | r;
            v[r] = unpack_h2(buf[p2idx(h, g) + off]);
        }
#pragma unroll
        for (int t = 0; t < 5; ++t) {
            const float C = c[t], SV = sv[t];
            const int msk = 1 << t;
#pragma unroll
            for (int r = 0; r < 32; ++r)
                if (!(r & msk)) bfly(C, SV, v[r], v[r | msk]);
        }
#pragma unroll
        for (int r = 0; r < 32; ++r) {
            int h = (hh << 5) | r;
            pout[h * 2048 + ll] = v[r];             // 256 B contiguous per 32 lanes
        }
    }
}

// ---------------------------------------------------------------------------
// Fallback fp32 path (proven round-0 kernels, inline trig, no ws needed).
// ---------------------------------------------------------------------------
__global__ __launch_bounds__(64) void rx_pass1(
        const float* __restrict__ phi, const float* __restrict__ thetas,
        float2* __restrict__ out) {
    __shared__ float2 lds[2048];
    const int lane = threadIdx.x;
    const int W = blockIdx.x;
    const int b = W >> 9;
    const int base = (W & 511) << 11;
    const float* ph = phi + ((size_t)b << NQ) + base;
    float2* op = out + ((size_t)b << NQ) + base;

    float c[11], sv[11];
#pragma unroll
    for (int beta = 0; beta < 11; ++beta) {
        float th = 0.5f * thetas[b * NQ + (NQ - 1 - beta)];
        c[beta]  = bcast_first(cosf(th));
        sv[beta] = bcast_first(sinf(th));
    }

    float2 v[32];
#pragma unroll
    for (int k4 = 0; k4 < 8; ++k4) {
        float4 t = *(const float4*)(ph + (k4 << 8) + (lane << 2));
        v[k4 * 4 + 0] = make_float2(t.x, 0.f);
        v[k4 * 4 + 1] = make_float2(t.y, 0.f);
        v[k4 * 4 + 2] = make_float2(t.z, 0.f);
        v[k4 * 4 + 3] = make_float2(t.w, 0.f);
    }

    const int regbit1[5]  = {0, 1, 8, 9, 10};
    const int regmask1[5] = {1, 2, 4, 8, 16};
#pragma unroll
    for (int t = 0; t < 5; ++t) {
        const float C = c[regbit1[t]], SV = sv[regbit1[t]];
        const int m = regmask1[t];
#pragma unroll
        for (int r = 0; r < 32; ++r)
            if (!(r & m)) bfly(C, SV, v[r], v[r | m]);
    }

#pragma unroll
    for (int k4 = 0; k4 < 8; ++k4) {
        int low0 = (k4 << 8) + (lane << 2);
        int s0 = swz1(low0);
        *(float4*)&lds[s0]     = make_float4(v[k4*4+0].x, v[k4*4+0].y, v[k4*4+1].x, v[k4*4+1].y);
        *(float4*)&lds[s0 + 2] = make_float4(v[k4*4+2].x, v[k4*4+2].y, v[k4*4+3].x, v[k4*4+3].y);
    }
    __syncthreads();

    {
        const int g = lane >> 2, lam = lane & 3;
        float2 w2[32];
#pragma unroll
        for (int r = 0; r < 32; ++r) {
            int l = (g << 7) | (r << 2) | lam;
            w2[r] = lds[swz1(l)];
        }
#pragma unroll
        for (int t = 0; t < 5; ++t) {
            const float C = c[2 + t], SV = sv[2 + t];
            const int m = 1 << t;
#pragma unroll
            for (int r = 0; r < 32; ++r)
                if (!(r & m)) bfly(C, SV, w2[r], w2[r | m]);
        }
#pragma unroll
        for (int r = 0; r < 32; ++r) {
            int l = (g << 7) | (r << 2) | lam;
            lds[swz1(l)] = w2[r];
        }
    }
    __syncthreads();

    float4 u[16];
#pragma unroll
    for (int m = 0; m < 16; ++m) {
        int l0 = (lane << 1) | ((m & 1) << 7) | (((m >> 1) & 1) << 8)
               | (((m >> 2) & 1) << 9) | (((m >> 3) & 1) << 10);
        u[m] = *(float4*)&lds[swz1(l0)];
    }
    {
        const float C = c[7], SV = sv[7];
#pragma unroll
        for (int m = 0; m < 16; m += 2) {
            float4 A = u[m], B = u[m + 1];
            u[m]     = make_float4(C*A.x + SV*B.y, C*A.y - SV*B.x, C*A.z + SV*B.w, C*A.w - SV*B.z);
            u[m + 1] = make_float4(C*B.x + SV*A.y, C*B.y - SV*A.x, C*B.z + SV*A.w, C*B.w - SV*A.z);
        }
    }
#pragma unroll
    for (int m = 0; m < 16; ++m) {
        int l0 = (lane << 1) | ((m & 1) << 7) | (((m >> 1) & 1) << 8)
               | (((m >> 2) & 1) << 9) | (((m >> 3) & 1) << 10);
        *(float4*)(op + l0) = u[m];
    }
}

__device__ __forceinline__ int ppos(int h, int q) {
    return (h << 4) + (((q ^ (h & 7) ^ ((h >> 5) & 7)) & 7) << 1);
}

__global__ __launch_bounds__(256) void rx_pass2(
        const float* __restrict__ thetas, float2* __restrict__ out) {
    __shared__ float2 buf[8192];
    const int tid = threadIdx.x;
    const int b = blockIdx.x >> 7;
    const int lb = blockIdx.x & 127;
    float2* p = out + ((size_t)b << NQ) + (lb << 4);

    float c[9], sv[9];
#pragma unroll
    for (int i = 0; i < 9; ++i) {
        float th = 0.5f * thetas[b * NQ + (8 - i)];
        c[i]  = bcast_first(cosf(th));
        sv[i] = bcast_first(sinf(th));
    }

#pragma unroll
    for (int i = 0; i < 16; ++i) {
        int f = (i << 8) | tid;
        int h = f >> 3, j = f & 7;
        float4 t = *(const float4*)(p + h * 2048 + (j << 1));
        *(float4*)&buf[ppos(h, j)] = t;
    }
    __syncthreads();

    {
        const int hl = tid & 31;
        const int j  = tid >> 5;
        float4 w[16];
#pragma unroll
        for (int m = 0; m < 16; ++m)
            w[m] = *(float4*)&buf[ppos((m << 5) | hl, j)];
#pragma unroll
        for (int t = 0; t < 4; ++t) {
            const float C = c[5 + t], SV = sv[5 + t];
            const int msk = 1 << t;
#pragma unroll
            for (int m = 0; m < 16; ++m)
                if (!(m & msk)) bfly4(C, SV, w[m], w[m | msk]);
        }
#pragma unroll
        for (int m = 0; m < 16; ++m)
            *(float4*)&buf[ppos((m << 5) | hl, j)] = w[m];
    }
    __syncthreads();

    {
        const int hh = tid >> 4;
        const int ll = tid & 15;
        float2 v[32];
#pragma unroll
        for (int r = 0; r < 32; ++r) {
            int h = (hh << 5) | r;
            v[r] = buf[ppos(h, ll >> 1) + (ll & 1)];
        }
#pragma unroll
        for (int t = 0; t < 5; ++t) {
            const float C = c[t], SV = sv[t];
            const int msk = 1 << t;
#pragma unroll
            for (int r = 0; r < 32; ++r)
                if (!(r & msk)) bfly(C, SV, v[r], v[r | msk]);
        }
#pragma unroll
        for (int r = 0; r < 32; ++r) {
            int h = (hh << 5) | r;
            p[h * 2048 + ll] = v[r];
        }
    }
}

extern "C" void kernel_launch(void* const* d_in, const int* in_sizes, int n_in,
                              void* d_out, int out_size, void* d_ws, size_t ws_size,
                              hipStream_t stream) {
    const float* phi    = (const float*)d_in[0];
    const float* thetas = (const float*)d_in[1];
    float2* out = (float2*)d_out;
    const size_t half_bytes = ((size_t)16 << NQ) * 4;    // 64 MiB half2 intermediate
    const size_t need = half_bytes + 4096;               // + trig table
    if (d_ws != nullptr && ws_size >= need) {
        unsigned int* ws = (unsigned int*)d_ws;
        float2* tab = (float2*)((char*)d_ws + half_bytes);
        rx_trig<<<1, 320, 0, stream>>>(thetas, tab);
        rx_pass1_h<<<8192, 64, 0, stream>>>(phi, tab, ws);
        rx_pass2_h<<<1024, 512, 0, stream>>>(tab, ws, out);
    } else {
        rx_pass1<<<8192, 64, 0, stream>>>(phi, thetas, out);
        rx_pass2<<<2048, 256, 0, stream>>>(thetas, out);
    }
}